// Round 14
// baseline (44.471 us; speedup 1.0000x reference)
//
#include <hip/hip_runtime.h>
#include <math.h>

// Dims: B=4, C=8, H=W=256
#define B_DIM 4
#define C_DIM 8
#define H_DIM 256
#define W_DIM 256
#define HW 65536
#define NPIX 262144

// ws layout (no zero-init required; every slot written every call):
// [0,     4096)   float pce[1024]
// [4096,  8192)   float pinter[1024]
// [8192, 16384)   int2  pcnt[1024]
// [16384, 16388)  float bound_num      (zeroed by k_row block 0; atomic-accumulated by k_cols)
// [16392, 16396)  uint  done2          (zeroed by k_row block 0)
// [65536,+1MB)    float lse[NPIX]
// [2MB, +256KB)   u64   wmask_g[32][256][4]   row seed bitmasks per (bc, y)

__device__ __forceinline__ float wave_reduce_f(float v) {
#pragma unroll
    for (int off = 32; off; off >>= 1) v += __shfl_xor(v, off, 64);
    return v;
}

// ------------- Kernel 1: fused softmax stats + row seed-mask generation -------------
__global__ void __launch_bounds__(256) k_row(
    const float* __restrict__ x, const int* __restrict__ tgt,
    float* __restrict__ lse_out, float* __restrict__ pce, float* __restrict__ pinter,
    int2* __restrict__ pcnt, unsigned long long* __restrict__ wmask_g,
    float* __restrict__ bound_num, unsigned int* __restrict__ done2) {
    int bi = blockIdx.x;                 // [0,1024): b*256 + y
    int b = bi >> 8, y = bi & 255;
    int i = threadIdx.x;                 // column
    int lane = i & 63, wid = i >> 6;
    size_t rowbase = (size_t)b * HW + (size_t)y * W_DIM;

    if (bi == 0 && i == 0) { *bound_num = 0.0f; *done2 = 0u; }  // visible to k_cols at kernel boundary

    // ---- softmax / CE / Dice stats ----
    const float* xb = x + (size_t)b * C_DIM * HW + (size_t)y * W_DIM + i;
    float v[C_DIM];
    float m = -1e30f;
#pragma unroll
    for (int c = 0; c < C_DIM; ++c) { v[c] = xb[(size_t)c * HW]; m = fmaxf(m, v[c]); }
    float s = 0.f;
#pragma unroll
    for (int c = 0; c < C_DIM; ++c) s += __expf(v[c] - m);
    float lse = m + __logf(s);
    lse_out[rowbase + i] = lse;

    int t = tgt[rowbase + i];
    bool valid_d = (t >= 0);
    bool valid_b = valid_d && (t < C_DIM);
    int tc = valid_b ? t : 0;
    float vt = v[0];
#pragma unroll
    for (int c = 1; c < C_DIM; ++c) vt = (tc == c) ? v[c] : vt;

    float ce = lse - vt;
    float inter = valid_b ? __expf(vt - lse) : 0.f;

    __shared__ float ws_ce[4], ws_in[4];
    __shared__ int ws_cd[4], ws_cb[4];
    float r_ce = wave_reduce_f(ce);
    float r_in = wave_reduce_f(inter);
    unsigned long long md = __ballot(valid_d);
    unsigned long long mbv = __ballot(valid_b);
    if (lane == 0) {
        ws_ce[wid] = r_ce; ws_in[wid] = r_in;
        ws_cd[wid] = __popcll(md); ws_cb[wid] = __popcll(mbv);
    }

    // ---- row seed bitmasks ----
    __shared__ unsigned long long wmask[C_DIM][4];
#pragma unroll
    for (int c = 0; c < C_DIM; ++c) {
        unsigned long long mc = __ballot(valid_b && (t == c));
        if (lane == 0) wmask[c][wid] = mc;
    }
    __syncthreads();

    if (i == 0) {
        pce[bi] = (ws_ce[0] + ws_ce[1]) + (ws_ce[2] + ws_ce[3]);
        pinter[bi] = (ws_in[0] + ws_in[1]) + (ws_in[2] + ws_in[3]);
        pcnt[bi] = make_int2((ws_cd[0] + ws_cd[1]) + (ws_cd[2] + ws_cd[3]),
                             (ws_cb[0] + ws_cb[1]) + (ws_cb[2] + ws_cb[3]));
    }
    if (i < 32) {   // store masks: [bc][y][w]
        int c = i >> 2, w = i & 3;
        wmask_g[((size_t)((b * C_DIM + c) * 256 + y) << 2) + w] = wmask[c][w];
    }
}

// ------------- Kernel 2: mask->d1 + outward envelope + boundary sum + last-block finalize ---
// grid 1024: blk -> bc = blk>>5, xt = (blk>>1)&15, yh = blk&1
#define LDS_PITCH 20
#define ENVELOPE(MA, MB)                                                        \
    {                                                                           \
        float4 qa0 = *(const float4*)&h[ybase][tx << 2];                        \
        float4 qb0 = *(const float4*)&h[ybase + 1][tx << 2];                    \
        MA.x = fminf(qa0.x, qb0.x + 1.0f); MB.x = fminf(qb0.x, qa0.x + 1.0f);   \
        MA.y = fminf(qa0.y, qb0.y + 1.0f); MB.y = fminf(qb0.y, qa0.y + 1.0f);   \
        MA.z = fminf(qa0.z, qb0.z + 1.0f); MB.z = fminf(qb0.z, qa0.z + 1.0f);   \
        MA.w = fminf(qa0.w, qb0.w + 1.0f); MB.w = fminf(qb0.w, qa0.w + 1.0f);   \
        int s = 1;                                                              \
        for (;;) {                                                              \
            int ra = max(ybase - s, 0);                                         \
            int rb = min(ybase + 1 + s, H_DIM - 1);                             \
            float4 qa = *(const float4*)&h[ra][tx << 2];                        \
            float4 qb = *(const float4*)&h[rb][tx << 2];                        \
            float s2a = (float)(s * s);                                         \
            float s2b = (float)((s + 1) * (s + 1));                             \
            MA.x = fminf(MA.x, fminf(qa.x + s2a, qb.x + s2b));                  \
            MA.y = fminf(MA.y, fminf(qa.y + s2a, qb.y + s2b));                  \
            MA.z = fminf(MA.z, fminf(qa.z + s2a, qb.z + s2b));                  \
            MA.w = fminf(MA.w, fminf(qa.w + s2a, qb.w + s2b));                  \
            MB.x = fminf(MB.x, fminf(qa.x + s2b, qb.x + s2a));                  \
            MB.y = fminf(MB.y, fminf(qa.y + s2b, qb.y + s2a));                  \
            MB.z = fminf(MB.z, fminf(qa.z + s2b, qb.z + s2a));                  \
            MB.w = fminf(MB.w, fminf(qa.w + s2b, qb.w + s2a));                  \
            float lmax = fmaxf(fmaxf(fmaxf(MA.x, MA.y), fmaxf(MA.z, MA.w)),     \
                               fmaxf(fmaxf(MB.x, MB.y), fmaxf(MB.z, MB.w)));    \
            ++s;                                                                \
            float st = (float)(s * s);                                          \
            if (s >= H_DIM || __all(st >= lmax)) break;                         \
        }                                                                       \
    }

__global__ void __launch_bounds__(256) k_cols(
    const unsigned long long* __restrict__ wmask_g, const float* __restrict__ x,
    const float* __restrict__ lse, const int* __restrict__ tgt,
    const float* __restrict__ pce, const float* __restrict__ pinter,
    const int2* __restrict__ pcnt,
    float* __restrict__ bound_num, unsigned int* __restrict__ done2,
    float* __restrict__ out) {
    int blk = blockIdx.x;            // [0, 1024)
    int bc = blk >> 5;               // [0, 32)
    int xt = (blk >> 1) & 15;
    int yh = blk & 1;
    int b = bc >> 3, c = bc & 7;
    int tid = threadIdx.x;
    int tx = tid & 3;
    int ybase = (yh << 7) + ((tid >> 2) << 1);   // 2-row tile
    int lane = tid & 63, wid = tid >> 6;

    __shared__ float h[H_DIM][LDS_PITCH];
    __shared__ int anyf[2];
    __shared__ float wsum[4];
    __shared__ int sh_last;
    __shared__ double dred[256];

    // hoist epilogue global loads: latency hides under mask->d1 compute + envelope
    size_t pixbase = (size_t)b * HW;
    size_t xplane = ((size_t)b * C_DIM + c) * HW;
    int x0 = (xt << 4) + (tx << 2);
    size_t row0 = (size_t)ybase * W_DIM + x0;
    size_t row1 = row0 + W_DIM;
    float4 xv0 = *(const float4*)(x + xplane + row0);
    float4 xv1 = *(const float4*)(x + xplane + row1);
    float4 lv0 = *(const float4*)(lse + pixbase + row0);
    float4 lv1 = *(const float4*)(lse + pixbase + row1);
    int4 tv0 = *(const int4*)(tgt + pixbase + row0);
    int4 tv1 = *(const int4*)(tgt + pixbase + row1);

    // load this row's masks (row = tid)
    const unsigned long long* mrow = wmask_g + ((size_t)(bc * 256 + tid) << 2);
    unsigned long long w0 = mrow[0], w1 = mrow[1], w2 = mrow[2], w3 = mrow[3];

    if (tid < 2) anyf[tid] = 0;
    __syncthreads();
    {
        unsigned long long orv = w0 | w1 | w2 | w3;
        unsigned long long andv = w0 & w1 & w2 & w3;
        unsigned long long bp = __ballot(orv != 0ull);
        unsigned long long bn = __ballot(andv != ~0ull);
        if (lane == 0) {
            if (bp) atomicOr(&anyf[0], 1);
            if (bn) atomicOr(&anyf[1], 1);
        }
    }

    // ---- reconstruct d1^2 for this row's 16 cols, both pols ----
    int wi = xt >> 2;
    int b0base = (xt & 3) << 4;
    int gc0 = xt << 4;
    int wbase = wi << 6;

    float d1sq0[16], d1sq1[16];
#pragma unroll
    for (int pol = 0; pol < 2; ++pol) {
        unsigned long long q0 = pol ? ~w0 : w0;
        unsigned long long q1 = pol ? ~w1 : w1;
        unsigned long long q2 = pol ? ~w2 : w2;
        unsigned long long q3 = pol ? ~w3 : w3;
        int h0p = q0 ? (63 - __builtin_clzll(q0)) : -100000;
        int h1p = q1 ? (127 - __builtin_clzll(q1)) : h0p;
        int h2p = q2 ? (191 - __builtin_clzll(q2)) : h1p;
        int lastp = (wi == 0) ? -100000 : (wi == 1) ? h0p : (wi == 2) ? h1p : h2p;
        int l3p = q3 ? (192 + __builtin_ctzll(q3)) : 100000;
        int l2p = q2 ? (128 + __builtin_ctzll(q2)) : l3p;
        int l1p = q1 ? (64 + __builtin_ctzll(q1)) : l2p;
        int nextp = (wi == 0) ? l1p : (wi == 1) ? l2p : (wi == 2) ? l3p : 100000;
        unsigned long long wn = (wi == 0) ? q0 : (wi == 1) ? q1 : (wi == 2) ? q2 : q3;
#pragma unroll
        for (int i2 = 0; i2 < 16; ++i2) {
            int b0 = b0base + i2;
            unsigned long long mle = wn & ((~0ull) >> (63 - b0));
            unsigned long long mge = wn & ((~0ull) << b0);
            int last = mle ? (wbase + 63 - __builtin_clzll(mle)) : lastp;
            int next = mge ? (wbase + __builtin_ctzll(mge)) : nextp;
            int gcol = gc0 + i2;
            int d1 = min(min(gcol - last, next - gcol), 512);
            float fd = (float)(d1 * d1);
            if (pol == 0) d1sq0[i2] = fd; else d1sq1[i2] = fd;
        }
    }

    // ---- phase A: pol0 plane ----
    *(float4*)&h[tid][0]  = make_float4(d1sq0[0], d1sq0[1], d1sq0[2], d1sq0[3]);
    *(float4*)&h[tid][4]  = make_float4(d1sq0[4], d1sq0[5], d1sq0[6], d1sq0[7]);
    *(float4*)&h[tid][8]  = make_float4(d1sq0[8], d1sq0[9], d1sq0[10], d1sq0[11]);
    *(float4*)&h[tid][12] = make_float4(d1sq0[12], d1sq0[13], d1sq0[14], d1sq0[15]);
    __syncthreads();
    float4 m0a, m0b;
    ENVELOPE(m0a, m0b)
    __syncthreads();

    // ---- phase B: pol1 plane (reuse LDS) ----
    *(float4*)&h[tid][0]  = make_float4(d1sq1[0], d1sq1[1], d1sq1[2], d1sq1[3]);
    *(float4*)&h[tid][4]  = make_float4(d1sq1[4], d1sq1[5], d1sq1[6], d1sq1[7]);
    *(float4*)&h[tid][8]  = make_float4(d1sq1[8], d1sq1[9], d1sq1[10], d1sq1[11]);
    *(float4*)&h[tid][12] = make_float4(d1sq1[12], d1sq1[13], d1sq1[14], d1sq1[15]);
    __syncthreads();
    float4 m1a, m1b;
    ENVELOPE(m1a, m1b)

    bool has_pos = anyf[0] != 0;
    bool has_neg = anyf[1] != 0;

    float lsum = 0.f;
#pragma unroll
    for (int iy = 0; iy < 2; ++iy) {
        float4 M0 = iy ? m0b : m0a;
        float4 M1 = iy ? m1b : m1a;
        float4 xv = iy ? xv1 : xv0;
        float4 lv = iy ? lv1 : lv0;
        int4 tv = iy ? tv1 : tv0;
#pragma unroll
        for (int j = 0; j < 4; ++j) {
            float d2o = (j == 0) ? M0.x : (j == 1) ? M0.y : (j == 2) ? M0.z : M0.w;
            float d2i = (j == 0) ? M1.x : (j == 1) ? M1.y : (j == 2) ? M1.z : M1.w;
            float dout = sqrtf(d2o), din = sqrtf(d2i);
            float sgn = has_pos ? (has_neg ? (dout - din) : dout) : 0.f;
            float xs = (j == 0) ? xv.x : (j == 1) ? xv.y : (j == 2) ? xv.z : xv.w;
            float ls = (j == 0) ? lv.x : (j == 1) ? lv.y : (j == 2) ? lv.z : lv.w;
            int tt   = (j == 0) ? tv.x : (j == 1) ? tv.y : (j == 2) ? tv.z : tv.w;
            bool vb = (tt >= 0) && (tt < C_DIM);
            float prob = __expf(xs - ls);
            lsum += vb ? prob * sgn : 0.f;
        }
    }

    float r2 = wave_reduce_f(lsum);
    if (lane == 0) wsum[wid] = r2;
    __syncthreads();
    if (tid == 0) {
        float bsum = (wsum[0] + wsum[1]) + (wsum[2] + wsum[3]);
        // fence-free chain: consume the returned old value so the wave waits (vmcnt)
        // for the bound add to commit at the coherent point BEFORE the counter bump.
        float old = atomicAdd(bound_num, bsum);
        asm volatile("" :: "v"(old));               // keep the dependency live
        unsigned int o = atomicAdd(done2, 1u);
        sh_last = (o == 1023u) ? 1 : 0;
    }
    __syncthreads();
    if (!sh_last) return;

    // ---- last block: finalize (no fences; k_row data visible via kernel boundary,
    //      bound_num read coherently via atomic) ----
    double s_ce = 0, s_in = 0, c_d = 0, c_b = 0;
    for (int k = tid; k < 1024; k += 256) {
        s_ce += (double)pce[k]; s_in += (double)pinter[k];
        int2 cc = pcnt[k]; c_d += (double)cc.x; c_b += (double)cc.y;
    }
    double sums[3]; double vin[3] = {s_ce, s_in, c_d * 4194304.0 + c_b};
    for (int q = 0; q < 3; ++q) {
        dred[tid] = vin[q];
        __syncthreads();
        for (int s2 = 128; s2; s2 >>= 1) { if (tid < s2) dred[tid] += dred[tid + s2]; __syncthreads(); }
        sums[q] = dred[0];
        __syncthreads();
    }
    if (tid == 0) {
        float btot = atomicAdd(bound_num, 0.0f);    // coherent read of the full sum
        double packed = sums[2];
        double cd = floor(packed / 4194304.0 + 1e-9);
        double cb = packed - cd * 4194304.0;
        double ce = sums[0] / (double)NPIX;
        double inter = sums[1];
        double card = cd + cb;
        double dice = 1.0 - (2.0 * inter + 1e-6) / (card + 1e-6);
        double dice_total = 0.1 * ce + 0.9 * dice;
        double bound = (double)btot / (cb + 1e-8);
        out[0] = (float)(0.1 * ce + 0.8 * dice_total + 0.1 * bound);
    }
}

extern "C" void kernel_launch(void* const* d_in, const int* in_sizes, int n_in,
                              void* d_out, int out_size, void* d_ws, size_t ws_size,
                              hipStream_t stream) {
    const float* x = (const float*)d_in[0];
    const int* tgt = (const int*)d_in[1];
    float* out = (float*)d_out;

    char* ws = (char*)d_ws;
    float* pce    = (float*)(ws + 0);
    float* pinter = (float*)(ws + 4096);
    int2*  pcnt   = (int2*)(ws + 8192);
    float* bound_num = (float*)(ws + 16384);
    unsigned int* done2 = (unsigned int*)(ws + 16392);
    float* lse    = (float*)(ws + 65536);
    unsigned long long* wmask_g = (unsigned long long*)(ws + (size_t)(2u << 20));

    k_row<<<1024, 256, 0, stream>>>(x, tgt, lse, pce, pinter, pcnt, wmask_g, bound_num, done2);
    k_cols<<<1024, 256, 0, stream>>>(wmask_g, x, lse, tgt, pce, pinter, pcnt,
                                     bound_num, done2, out);
}

// Round 15
// 27.982 us; speedup vs baseline: 1.5893x; 1.5893x over previous
//
#include <hip/hip_runtime.h>
#include <math.h>

// Dims: B=4, C=8, H=W=256
#define B_DIM 4
#define C_DIM 8
#define H_DIM 256
#define W_DIM 256
#define HW 65536
#define NPIX 262144

// ws layout (zero-init of counters done by k_row block 0; visible at kernel boundary):
// [0,     4096)   float pce[1024]
// [4096,  8192)   float pinter[1024]
// [8192, 16384)   int2  pcnt[1024]
// [16384, 20480)  float bound_part[32] @ stride 32 floats (128B lines)
// [20480, 24576)  uint  cnt[32]        @ stride 32 uints  (128B lines)
// [24576, 24580)  uint  gdone
// [65536,+1MB)    float lse[NPIX]
// [2MB, +256KB)   u64   wmask_g[32][256][4]   row seed bitmasks per (bc, y)

__device__ __forceinline__ float wave_reduce_f(float v) {
#pragma unroll
    for (int off = 32; off; off >>= 1) v += __shfl_xor(v, off, 64);
    return v;
}

// ------------- Kernel 1: fused softmax stats + row seed-mask generation -------------
__global__ void __launch_bounds__(256) k_row(
    const float* __restrict__ x, const int* __restrict__ tgt,
    float* __restrict__ lse_out, float* __restrict__ pce, float* __restrict__ pinter,
    int2* __restrict__ pcnt, unsigned long long* __restrict__ wmask_g,
    float* __restrict__ bound_part, unsigned int* __restrict__ cnt,
    unsigned int* __restrict__ gdone) {
    int bi = blockIdx.x;                 // [0,1024): b*256 + y
    int b = bi >> 8, y = bi & 255;
    int i = threadIdx.x;                 // column
    int lane = i & 63, wid = i >> 6;
    size_t rowbase = (size_t)b * HW + (size_t)y * W_DIM;

    if (bi == 0) {                       // zero hierarchical counters (kernel-boundary visible)
        if (i < 32) { bound_part[i << 5] = 0.0f; cnt[i << 5] = 0u; }
        if (i == 32) *gdone = 0u;
    }

    // ---- softmax / CE / Dice stats ----
    const float* xb = x + (size_t)b * C_DIM * HW + (size_t)y * W_DIM + i;
    float v[C_DIM];
    float m = -1e30f;
#pragma unroll
    for (int c = 0; c < C_DIM; ++c) { v[c] = xb[(size_t)c * HW]; m = fmaxf(m, v[c]); }
    float s = 0.f;
#pragma unroll
    for (int c = 0; c < C_DIM; ++c) s += __expf(v[c] - m);
    float lse = m + __logf(s);
    lse_out[rowbase + i] = lse;

    int t = tgt[rowbase + i];
    bool valid_d = (t >= 0);
    bool valid_b = valid_d && (t < C_DIM);
    int tc = valid_b ? t : 0;
    float vt = v[0];
#pragma unroll
    for (int c = 1; c < C_DIM; ++c) vt = (tc == c) ? v[c] : vt;

    float ce = lse - vt;
    float inter = valid_b ? __expf(vt - lse) : 0.f;

    __shared__ float ws_ce[4], ws_in[4];
    __shared__ int ws_cd[4], ws_cb[4];
    float r_ce = wave_reduce_f(ce);
    float r_in = wave_reduce_f(inter);
    unsigned long long md = __ballot(valid_d);
    unsigned long long mbv = __ballot(valid_b);
    if (lane == 0) {
        ws_ce[wid] = r_ce; ws_in[wid] = r_in;
        ws_cd[wid] = __popcll(md); ws_cb[wid] = __popcll(mbv);
    }

    // ---- row seed bitmasks ----
    __shared__ unsigned long long wmask[C_DIM][4];
#pragma unroll
    for (int c = 0; c < C_DIM; ++c) {
        unsigned long long mc = __ballot(valid_b && (t == c));
        if (lane == 0) wmask[c][wid] = mc;
    }
    __syncthreads();

    if (i == 0) {
        pce[bi] = (ws_ce[0] + ws_ce[1]) + (ws_ce[2] + ws_ce[3]);
        pinter[bi] = (ws_in[0] + ws_in[1]) + (ws_in[2] + ws_in[3]);
        pcnt[bi] = make_int2((ws_cd[0] + ws_cd[1]) + (ws_cd[2] + ws_cd[3]),
                             (ws_cb[0] + ws_cb[1]) + (ws_cb[2] + ws_cb[3]));
    }
    if (i < 32) {   // store masks: [bc][y][w]
        int c = i >> 2, w = i & 3;
        wmask_g[((size_t)((b * C_DIM + c) * 256 + y) << 2) + w] = wmask[c][w];
    }
}

// ------------- Kernel 2: mask->d1 + outward envelope + bound + hierarchical finalize ---
// grid 1024: blk -> bc = blk>>5, xt = (blk>>1)&15, yh = blk&1
#define LDS_PITCH 20
#define ENVELOPE(MA, MB)                                                        \
    {                                                                           \
        float4 qa0 = *(const float4*)&h[ybase][tx << 2];                        \
        float4 qb0 = *(const float4*)&h[ybase + 1][tx << 2];                    \
        MA.x = fminf(qa0.x, qb0.x + 1.0f); MB.x = fminf(qb0.x, qa0.x + 1.0f);   \
        MA.y = fminf(qa0.y, qb0.y + 1.0f); MB.y = fminf(qb0.y, qa0.y + 1.0f);   \
        MA.z = fminf(qa0.z, qb0.z + 1.0f); MB.z = fminf(qb0.z, qa0.z + 1.0f);   \
        MA.w = fminf(qa0.w, qb0.w + 1.0f); MB.w = fminf(qb0.w, qa0.w + 1.0f);   \
        int s = 1;                                                              \
        for (;;) {                                                              \
            int ra = max(ybase - s, 0);                                         \
            int rb = min(ybase + 1 + s, H_DIM - 1);                             \
            float4 qa = *(const float4*)&h[ra][tx << 2];                        \
            float4 qb = *(const float4*)&h[rb][tx << 2];                        \
            float s2a = (float)(s * s);                                         \
            float s2b = (float)((s + 1) * (s + 1));                             \
            MA.x = fminf(MA.x, fminf(qa.x + s2a, qb.x + s2b));                  \
            MA.y = fminf(MA.y, fminf(qa.y + s2a, qb.y + s2b));                  \
            MA.z = fminf(MA.z, fminf(qa.z + s2a, qb.z + s2b));                  \
            MA.w = fminf(MA.w, fminf(qa.w + s2a, qb.w + s2b));                  \
            MB.x = fminf(MB.x, fminf(qa.x + s2b, qb.x + s2a));                  \
            MB.y = fminf(MB.y, fminf(qa.y + s2b, qb.y + s2a));                  \
            MB.z = fminf(MB.z, fminf(qa.z + s2b, qb.z + s2a));                  \
            MB.w = fminf(MB.w, fminf(qa.w + s2b, qb.w + s2a));                  \
            float lmax = fmaxf(fmaxf(fmaxf(MA.x, MA.y), fmaxf(MA.z, MA.w)),     \
                               fmaxf(fmaxf(MB.x, MB.y), fmaxf(MB.z, MB.w)));    \
            ++s;                                                                \
            float st = (float)(s * s);                                          \
            if (s >= H_DIM || __all(st >= lmax)) break;                         \
        }                                                                       \
    }

__global__ void __launch_bounds__(256) k_cols(
    const unsigned long long* __restrict__ wmask_g, const float* __restrict__ x,
    const float* __restrict__ lse, const int* __restrict__ tgt,
    const float* __restrict__ pce, const float* __restrict__ pinter,
    const int2* __restrict__ pcnt,
    float* __restrict__ bound_part, unsigned int* __restrict__ cnt,
    unsigned int* __restrict__ gdone, float* __restrict__ out) {
    int blk = blockIdx.x;            // [0, 1024)
    int bc = blk >> 5;               // [0, 32)
    int xt = (blk >> 1) & 15;
    int yh = blk & 1;
    int b = bc >> 3, c = bc & 7;
    int tid = threadIdx.x;
    int tx = tid & 3;
    int ybase = (yh << 7) + ((tid >> 2) << 1);   // 2-row tile
    int lane = tid & 63, wid = tid >> 6;

    __shared__ float h[H_DIM][LDS_PITCH];
    __shared__ int anyf[2];
    __shared__ float wsum[4];
    __shared__ int sh_last;
    __shared__ double dred[256];
    __shared__ float bpart_s[32];

    // hoist epilogue global loads
    size_t pixbase = (size_t)b * HW;
    size_t xplane = ((size_t)b * C_DIM + c) * HW;
    int x0 = (xt << 4) + (tx << 2);
    size_t row0 = (size_t)ybase * W_DIM + x0;
    size_t row1 = row0 + W_DIM;
    float4 xv0 = *(const float4*)(x + xplane + row0);
    float4 xv1 = *(const float4*)(x + xplane + row1);
    float4 lv0 = *(const float4*)(lse + pixbase + row0);
    float4 lv1 = *(const float4*)(lse + pixbase + row1);
    int4 tv0 = *(const int4*)(tgt + pixbase + row0);
    int4 tv1 = *(const int4*)(tgt + pixbase + row1);

    // load this row's masks (row = tid)
    const unsigned long long* mrow = wmask_g + ((size_t)(bc * 256 + tid) << 2);
    unsigned long long w0 = mrow[0], w1 = mrow[1], w2 = mrow[2], w3 = mrow[3];

    if (tid < 2) anyf[tid] = 0;
    __syncthreads();
    {
        unsigned long long orv = w0 | w1 | w2 | w3;
        unsigned long long andv = w0 & w1 & w2 & w3;
        unsigned long long bp = __ballot(orv != 0ull);
        unsigned long long bn = __ballot(andv != ~0ull);
        if (lane == 0) {
            if (bp) atomicOr(&anyf[0], 1);
            if (bn) atomicOr(&anyf[1], 1);
        }
    }

    // ---- reconstruct d1^2 for this row's 16 cols, both pols ----
    int wi = xt >> 2;
    int b0base = (xt & 3) << 4;
    int gc0 = xt << 4;
    int wbase = wi << 6;

    float d1sq0[16], d1sq1[16];
#pragma unroll
    for (int pol = 0; pol < 2; ++pol) {
        unsigned long long q0 = pol ? ~w0 : w0;
        unsigned long long q1 = pol ? ~w1 : w1;
        unsigned long long q2 = pol ? ~w2 : w2;
        unsigned long long q3 = pol ? ~w3 : w3;
        int h0p = q0 ? (63 - __builtin_clzll(q0)) : -100000;
        int h1p = q1 ? (127 - __builtin_clzll(q1)) : h0p;
        int h2p = q2 ? (191 - __builtin_clzll(q2)) : h1p;
        int lastp = (wi == 0) ? -100000 : (wi == 1) ? h0p : (wi == 2) ? h1p : h2p;
        int l3p = q3 ? (192 + __builtin_ctzll(q3)) : 100000;
        int l2p = q2 ? (128 + __builtin_ctzll(q2)) : l3p;
        int l1p = q1 ? (64 + __builtin_ctzll(q1)) : l2p;
        int nextp = (wi == 0) ? l1p : (wi == 1) ? l2p : (wi == 2) ? l3p : 100000;
        unsigned long long wn = (wi == 0) ? q0 : (wi == 1) ? q1 : (wi == 2) ? q2 : q3;
#pragma unroll
        for (int i2 = 0; i2 < 16; ++i2) {
            int b0 = b0base + i2;
            unsigned long long mle = wn & ((~0ull) >> (63 - b0));
            unsigned long long mge = wn & ((~0ull) << b0);
            int last = mle ? (wbase + 63 - __builtin_clzll(mle)) : lastp;
            int next = mge ? (wbase + __builtin_ctzll(mge)) : nextp;
            int gcol = gc0 + i2;
            int d1 = min(min(gcol - last, next - gcol), 512);
            float fd = (float)(d1 * d1);
            if (pol == 0) d1sq0[i2] = fd; else d1sq1[i2] = fd;
        }
    }

    // ---- phase A: pol0 plane ----
    *(float4*)&h[tid][0]  = make_float4(d1sq0[0], d1sq0[1], d1sq0[2], d1sq0[3]);
    *(float4*)&h[tid][4]  = make_float4(d1sq0[4], d1sq0[5], d1sq0[6], d1sq0[7]);
    *(float4*)&h[tid][8]  = make_float4(d1sq0[8], d1sq0[9], d1sq0[10], d1sq0[11]);
    *(float4*)&h[tid][12] = make_float4(d1sq0[12], d1sq0[13], d1sq0[14], d1sq0[15]);
    __syncthreads();
    float4 m0a, m0b;
    ENVELOPE(m0a, m0b)
    __syncthreads();

    // ---- phase B: pol1 plane (reuse LDS) ----
    *(float4*)&h[tid][0]  = make_float4(d1sq1[0], d1sq1[1], d1sq1[2], d1sq1[3]);
    *(float4*)&h[tid][4]  = make_float4(d1sq1[4], d1sq1[5], d1sq1[6], d1sq1[7]);
    *(float4*)&h[tid][8]  = make_float4(d1sq1[8], d1sq1[9], d1sq1[10], d1sq1[11]);
    *(float4*)&h[tid][12] = make_float4(d1sq1[12], d1sq1[13], d1sq1[14], d1sq1[15]);
    __syncthreads();
    float4 m1a, m1b;
    ENVELOPE(m1a, m1b)

    bool has_pos = anyf[0] != 0;
    bool has_neg = anyf[1] != 0;

    float lsum = 0.f;
#pragma unroll
    for (int iy = 0; iy < 2; ++iy) {
        float4 M0 = iy ? m0b : m0a;
        float4 M1 = iy ? m1b : m1a;
        float4 xv = iy ? xv1 : xv0;
        float4 lv = iy ? lv1 : lv0;
        int4 tv = iy ? tv1 : tv0;
#pragma unroll
        for (int j = 0; j < 4; ++j) {
            float d2o = (j == 0) ? M0.x : (j == 1) ? M0.y : (j == 2) ? M0.z : M0.w;
            float d2i = (j == 0) ? M1.x : (j == 1) ? M1.y : (j == 2) ? M1.z : M1.w;
            float dout = sqrtf(d2o), din = sqrtf(d2i);
            float sgn = has_pos ? (has_neg ? (dout - din) : dout) : 0.f;
            float xs = (j == 0) ? xv.x : (j == 1) ? xv.y : (j == 2) ? xv.z : xv.w;
            float ls = (j == 0) ? lv.x : (j == 1) ? lv.y : (j == 2) ? lv.z : lv.w;
            int tt   = (j == 0) ? tv.x : (j == 1) ? tv.y : (j == 2) ? tv.z : tv.w;
            bool vb = (tt >= 0) && (tt < C_DIM);
            float prob = __expf(xs - ls);
            lsum += vb ? prob * sgn : 0.f;
        }
    }

    float r2 = wave_reduce_f(lsum);
    if (lane == 0) wsum[wid] = r2;
    __syncthreads();
    if (tid == 0) {
        float bsum = (wsum[0] + wsum[1]) + (wsum[2] + wsum[3]);
        // hierarchical fence-free chain: bound add committed (returned value consumed)
        // before per-bc counter bump; last-of-bc bumps gdone; last-of-all finalizes.
        float old = atomicAdd(&bound_part[bc << 5], bsum);
        asm volatile("" :: "v"(old));
        unsigned int o = atomicAdd(&cnt[bc << 5], 1u);
        int lastflag = 0;
        if (o == 31u) {
            unsigned int g = atomicAdd(gdone, 1u);
            lastflag = (g == 31u) ? 1 : 0;
        }
        sh_last = lastflag;
    }
    __syncthreads();
    if (!sh_last) return;

    // ---- globally-last block: finalize ----
    double s_ce = 0, s_in = 0, c_d = 0, c_b = 0;
    for (int k = tid; k < 1024; k += 256) {
        s_ce += (double)pce[k]; s_in += (double)pinter[k];
        int2 cc = pcnt[k]; c_d += (double)cc.x; c_b += (double)cc.y;
    }
    double sums[3]; double vin[3] = {s_ce, s_in, c_d * 4194304.0 + c_b};
    for (int q = 0; q < 3; ++q) {
        dred[tid] = vin[q];
        __syncthreads();
        for (int s2 = 128; s2; s2 >>= 1) { if (tid < s2) dred[tid] += dred[tid + s2]; __syncthreads(); }
        sums[q] = dred[0];
        __syncthreads();
    }
    if (tid < 32) bpart_s[tid] = atomicAdd(&bound_part[tid << 5], 0.0f);  // coherent reads
    __syncthreads();
    if (tid == 0) {
        double btot = 0.0;
        for (int k = 0; k < 32; ++k) btot += (double)bpart_s[k];
        double packed = sums[2];
        double cd = floor(packed / 4194304.0 + 1e-9);
        double cb = packed - cd * 4194304.0;
        double ce = sums[0] / (double)NPIX;
        double inter = sums[1];
        double card = cd + cb;
        double dice = 1.0 - (2.0 * inter + 1e-6) / (card + 1e-6);
        double dice_total = 0.1 * ce + 0.9 * dice;
        double bound = btot / (cb + 1e-8);
        out[0] = (float)(0.1 * ce + 0.8 * dice_total + 0.1 * bound);
    }
}

extern "C" void kernel_launch(void* const* d_in, const int* in_sizes, int n_in,
                              void* d_out, int out_size, void* d_ws, size_t ws_size,
                              hipStream_t stream) {
    const float* x = (const float*)d_in[0];
    const int* tgt = (const int*)d_in[1];
    float* out = (float*)d_out;

    char* ws = (char*)d_ws;
    float* pce    = (float*)(ws + 0);
    float* pinter = (float*)(ws + 4096);
    int2*  pcnt   = (int2*)(ws + 8192);
    float* bound_part = (float*)(ws + 16384);
    unsigned int* cnt = (unsigned int*)(ws + 20480);
    unsigned int* gdone = (unsigned int*)(ws + 24576);
    float* lse    = (float*)(ws + 65536);
    unsigned long long* wmask_g = (unsigned long long*)(ws + (size_t)(2u << 20));

    k_row<<<1024, 256, 0, stream>>>(x, tgt, lse, pce, pinter, pcnt, wmask_g,
                                    bound_part, cnt, gdone);
    k_cols<<<1024, 256, 0, stream>>>(wmask_g, x, lse, tgt, pce, pinter, pcnt,
                                     bound_part, cnt, gdone, out);
}

// Round 16
// 22.016 us; speedup vs baseline: 2.0200x; 1.2710x over previous
//
#include <hip/hip_runtime.h>
#include <math.h>

// Dims: B=4, C=8, H=W=256
#define B_DIM 4
#define C_DIM 8
#define H_DIM 256
#define W_DIM 256
#define HW 65536
#define NPIX 262144

// ws layout (counters zeroed by k_row block 0; visible at kernel boundary):
// [0,     4096)   float pce[1024]
// [4096,  8192)   float pinter[1024]
// [8192, 16384)   int2  pcnt[1024]
// [16384, 20480)  float bound_part[32] @ stride 32 floats (128B lines)
// [20480, 24576)  uint  cnt[32]        @ stride 32 uints  (128B lines)
// [24576, 24580)  uint  gdone
// [65536,+1MB)    float lse[NPIX]
// [2MB, +256KB)   u64   wmask_g[32][256][4]   row seed bitmasks per (bc, y)

__device__ __forceinline__ float wave_reduce_f(float v) {
#pragma unroll
    for (int off = 32; off; off >>= 1) v += __shfl_xor(v, off, 64);
    return v;
}

// ------------- Kernel 1: fused softmax stats + row seed-mask generation -------------
__global__ void __launch_bounds__(256) k_row(
    const float* __restrict__ x, const int* __restrict__ tgt,
    float* __restrict__ lse_out, float* __restrict__ pce, float* __restrict__ pinter,
    int2* __restrict__ pcnt, unsigned long long* __restrict__ wmask_g,
    float* __restrict__ bound_part, unsigned int* __restrict__ cnt,
    unsigned int* __restrict__ gdone) {
    int bi = blockIdx.x;                 // [0,1024): b*256 + y
    int b = bi >> 8, y = bi & 255;
    int i = threadIdx.x;                 // column
    int lane = i & 63, wid = i >> 6;
    size_t rowbase = (size_t)b * HW + (size_t)y * W_DIM;

    if (bi == 0) {                       // zero hierarchical counters (kernel-boundary visible)
        if (i < 32) { bound_part[i << 5] = 0.0f; cnt[i << 5] = 0u; }
        if (i == 32) *gdone = 0u;
    }

    // ---- softmax / CE / Dice stats ----
    const float* xb = x + (size_t)b * C_DIM * HW + (size_t)y * W_DIM + i;
    float v[C_DIM];
    float m = -1e30f;
#pragma unroll
    for (int c = 0; c < C_DIM; ++c) { v[c] = xb[(size_t)c * HW]; m = fmaxf(m, v[c]); }
    float s = 0.f;
#pragma unroll
    for (int c = 0; c < C_DIM; ++c) s += __expf(v[c] - m);
    float lse = m + __logf(s);
    lse_out[rowbase + i] = lse;

    int t = tgt[rowbase + i];
    bool valid_d = (t >= 0);
    bool valid_b = valid_d && (t < C_DIM);
    int tc = valid_b ? t : 0;
    float vt = v[0];
#pragma unroll
    for (int c = 1; c < C_DIM; ++c) vt = (tc == c) ? v[c] : vt;

    float ce = lse - vt;
    float inter = valid_b ? __expf(vt - lse) : 0.f;

    __shared__ float ws_ce[4], ws_in[4];
    __shared__ int ws_cd[4], ws_cb[4];
    float r_ce = wave_reduce_f(ce);
    float r_in = wave_reduce_f(inter);
    unsigned long long md = __ballot(valid_d);
    unsigned long long mbv = __ballot(valid_b);
    if (lane == 0) {
        ws_ce[wid] = r_ce; ws_in[wid] = r_in;
        ws_cd[wid] = __popcll(md); ws_cb[wid] = __popcll(mbv);
    }

    // ---- row seed bitmasks ----
    __shared__ unsigned long long wmask[C_DIM][4];
#pragma unroll
    for (int c = 0; c < C_DIM; ++c) {
        unsigned long long mc = __ballot(valid_b && (t == c));
        if (lane == 0) wmask[c][wid] = mc;
    }
    __syncthreads();

    if (i == 0) {
        pce[bi] = (ws_ce[0] + ws_ce[1]) + (ws_ce[2] + ws_ce[3]);
        pinter[bi] = (ws_in[0] + ws_in[1]) + (ws_in[2] + ws_in[3]);
        pcnt[bi] = make_int2((ws_cd[0] + ws_cd[1]) + (ws_cd[2] + ws_cd[3]),
                             (ws_cb[0] + ws_cb[1]) + (ws_cb[2] + ws_cb[3]));
    }
    if (i < 32) {   // store masks: [bc][y][w]
        int c = i >> 2, w = i & 3;
        wmask_g[((size_t)((b * C_DIM + c) * 256 + y) << 2) + w] = wmask[c][w];
    }
}

// ------------- Kernel 2: mask->d1 (incremental scan) + outward envelope + finalize ---------
// grid 512: blk -> bc = blk>>4, xt = blk&15.  512 threads/block.
// staging: t<256 -> pol0 row t; t>=256 -> pol1 row t-256; 16-col incremental run scan.
// envelope: thread tile 2 rows x 4 cols over all 256 rows (ty = tid>>2, 128 values).
#define LDS_PITCH 20
#define ENVELOPE(H, MA, MB)                                                     \
    {                                                                           \
        float4 qa0 = *(const float4*)&H[ybase][tx << 2];                        \
        float4 qb0 = *(const float4*)&H[ybase + 1][tx << 2];                    \
        MA.x = fminf(qa0.x, qb0.x + 1.0f); MB.x = fminf(qb0.x, qa0.x + 1.0f);   \
        MA.y = fminf(qa0.y, qb0.y + 1.0f); MB.y = fminf(qb0.y, qa0.y + 1.0f);   \
        MA.z = fminf(qa0.z, qb0.z + 1.0f); MB.z = fminf(qb0.z, qa0.z + 1.0f);   \
        MA.w = fminf(qa0.w, qb0.w + 1.0f); MB.w = fminf(qb0.w, qa0.w + 1.0f);   \
        int s = 1;                                                              \
        for (;;) {                                                              \
            int ra = max(ybase - s, 0);                                         \
            int rb = min(ybase + 1 + s, H_DIM - 1);                             \
            float4 qa = *(const float4*)&H[ra][tx << 2];                        \
            float4 qb = *(const float4*)&H[rb][tx << 2];                        \
            float s2a = (float)(s * s);                                         \
            float s2b = (float)((s + 1) * (s + 1));                             \
            MA.x = fminf(MA.x, fminf(qa.x + s2a, qb.x + s2b));                  \
            MA.y = fminf(MA.y, fminf(qa.y + s2a, qb.y + s2b));                  \
            MA.z = fminf(MA.z, fminf(qa.z + s2a, qb.z + s2b));                  \
            MA.w = fminf(MA.w, fminf(qa.w + s2a, qb.w + s2b));                  \
            MB.x = fminf(MB.x, fminf(qa.x + s2b, qb.x + s2a));                  \
            MB.y = fminf(MB.y, fminf(qa.y + s2b, qb.y + s2a));                  \
            MB.z = fminf(MB.z, fminf(qa.z + s2b, qb.z + s2a));                  \
            MB.w = fminf(MB.w, fminf(qa.w + s2b, qb.w + s2a));                  \
            float lmax = fmaxf(fmaxf(fmaxf(MA.x, MA.y), fmaxf(MA.z, MA.w)),     \
                               fmaxf(fmaxf(MB.x, MB.y), fmaxf(MB.z, MB.w)));    \
            ++s;                                                                \
            float st = (float)(s * s);                                          \
            if (s >= H_DIM || __all(st >= lmax)) break;                         \
        }                                                                       \
    }

__global__ void __launch_bounds__(512) k_cols(
    const unsigned long long* __restrict__ wmask_g, const float* __restrict__ x,
    const float* __restrict__ lse, const int* __restrict__ tgt,
    const float* __restrict__ pce, const float* __restrict__ pinter,
    const int2* __restrict__ pcnt,
    float* __restrict__ bound_part, unsigned int* __restrict__ cnt,
    unsigned int* __restrict__ gdone, float* __restrict__ out) {
    int blk = blockIdx.x;            // [0, 512)
    int bc = blk >> 4;               // [0, 32)
    int xt = blk & 15;
    int b = bc >> 3, c = bc & 7;
    int tid = threadIdx.x;           // [0, 512)
    int tx = tid & 3;
    int ybase = (tid >> 2) << 1;     // [0, 256) step 2 (envelope mapping)
    int lane = tid & 63, wid = tid >> 6;

    __shared__ float h0s[H_DIM][LDS_PITCH];
    __shared__ float h1s[H_DIM][LDS_PITCH];
    __shared__ int anyf[2];
    __shared__ float wsum[8];
    __shared__ int sh_last;
    __shared__ double dred[512];

    // hoist epilogue global loads (latency hides under staging + envelope)
    size_t pixbase = (size_t)b * HW;
    size_t xplane = ((size_t)b * C_DIM + c) * HW;
    int x0 = (xt << 4) + (tx << 2);
    size_t row0 = (size_t)ybase * W_DIM + x0;
    size_t row1 = row0 + W_DIM;
    float4 xv0 = *(const float4*)(x + xplane + row0);
    float4 xv1 = *(const float4*)(x + xplane + row1);
    float4 lv0 = *(const float4*)(lse + pixbase + row0);
    float4 lv1 = *(const float4*)(lse + pixbase + row1);
    int4 tv0 = *(const int4*)(tgt + pixbase + row0);
    int4 tv1 = *(const int4*)(tgt + pixbase + row1);

    // ---- staging: this thread reconstructs one row, one polarity ----
    int srow = tid & 255;
    int pol = tid >> 8;              // 0 or 1
    const unsigned long long* mrow = wmask_g + ((size_t)(bc * 256 + srow) << 2);
    unsigned long long w0 = mrow[0], w1 = mrow[1], w2 = mrow[2], w3 = mrow[3];

    if (tid < 2) anyf[tid] = 0;
    __syncthreads();
    if (pol == 0) {   // any_pos from pol0 stagers; any_neg from pol1 stagers
        unsigned long long orv = w0 | w1 | w2 | w3;
        unsigned long long bp = __ballot(orv != 0ull);
        if (lane == 0 && bp) atomicOr(&anyf[0], 1);
    } else {
        unsigned long long andv = w0 & w1 & w2 & w3;
        unsigned long long bn = __ballot(andv != ~0ull);
        if (lane == 0 && bn) atomicOr(&anyf[1], 1);
    }

    {
        unsigned long long q0 = pol ? ~w0 : w0;
        unsigned long long q1 = pol ? ~w1 : w1;
        unsigned long long q2 = pol ? ~w2 : w2;
        unsigned long long q3 = pol ? ~w3 : w3;
        int wi = xt >> 2;
        int b0base = (xt & 3) << 4;
        int gc0 = xt << 4;
        int wbase = wi << 6;
        // cross-word prefix (highest set < this word) / suffix (lowest set > this word)
        int h0p = q0 ? (63 - __builtin_clzll(q0)) : -100000;
        int h1p = q1 ? (127 - __builtin_clzll(q1)) : h0p;
        int h2p = q2 ? (191 - __builtin_clzll(q2)) : h1p;
        int lastp = (wi == 0) ? -100000 : (wi == 1) ? h0p : (wi == 2) ? h1p : h2p;
        int l3p = q3 ? (192 + __builtin_ctzll(q3)) : 100000;
        int l2p = q2 ? (128 + __builtin_ctzll(q2)) : l3p;
        int l1p = q1 ? (64 + __builtin_ctzll(q1)) : l2p;
        int nextp = (wi == 0) ? l1p : (wi == 1) ? l2p : (wi == 2) ? l3p : 100000;
        unsigned long long wn = (wi == 0) ? q0 : (wi == 1) ? q1 : (wi == 2) ? q2 : q3;
        // within-word bits below/above the 16-col window
        unsigned long long lowmask = (b0base == 0) ? 0ull : ((~0ull) >> (64 - b0base));
        unsigned long long wlow = wn & lowmask;
        int lastw = wlow ? (wbase + 63 - __builtin_clzll(wlow)) : lastp;
        int hib = b0base + 16;
        unsigned long long whigh = (hib == 64) ? 0ull : (wn & ((~0ull) << hib));
        int nextw = whigh ? (wbase + __builtin_ctzll(whigh)) : nextp;
        unsigned int wseg = (unsigned int)((wn >> b0base) & 0xFFFFull);

        // incremental forward/backward run scans (exactly the ballot d1)
        int d1l[16], d1r[16];
        int dl = gc0 - lastw;
#pragma unroll
        for (int i2 = 0; i2 < 16; ++i2) {
            dl = ((wseg >> i2) & 1u) ? 0 : dl;
            d1l[i2] = dl;
            ++dl;
        }
        int dr = nextw - (gc0 + 15);
#pragma unroll
        for (int i2 = 15; i2 >= 0; --i2) {
            dr = ((wseg >> i2) & 1u) ? 0 : dr;
            d1r[i2] = dr;
            ++dr;
        }
        float fd[16];
#pragma unroll
        for (int i2 = 0; i2 < 16; ++i2) {
            int d1 = min(min(d1l[i2], d1r[i2]), 512);
            fd[i2] = (float)d1 * (float)d1;
        }
        float (*hp)[LDS_PITCH] = pol ? h1s : h0s;
        *(float4*)&hp[srow][0]  = make_float4(fd[0], fd[1], fd[2], fd[3]);
        *(float4*)&hp[srow][4]  = make_float4(fd[4], fd[5], fd[6], fd[7]);
        *(float4*)&hp[srow][8]  = make_float4(fd[8], fd[9], fd[10], fd[11]);
        *(float4*)&hp[srow][12] = make_float4(fd[12], fd[13], fd[14], fd[15]);
    }
    __syncthreads();

    float4 m0a, m0b, m1a, m1b;
    ENVELOPE(h0s, m0a, m0b)
    ENVELOPE(h1s, m1a, m1b)

    bool has_pos = anyf[0] != 0;
    bool has_neg = anyf[1] != 0;

    float lsum = 0.f;
#pragma unroll
    for (int iy = 0; iy < 2; ++iy) {
        float4 M0 = iy ? m0b : m0a;
        float4 M1 = iy ? m1b : m1a;
        float4 xv = iy ? xv1 : xv0;
        float4 lv = iy ? lv1 : lv0;
        int4 tv = iy ? tv1 : tv0;
#pragma unroll
        for (int j = 0; j < 4; ++j) {
            float d2o = (j == 0) ? M0.x : (j == 1) ? M0.y : (j == 2) ? M0.z : M0.w;
            float d2i = (j == 0) ? M1.x : (j == 1) ? M1.y : (j == 2) ? M1.z : M1.w;
            float dout = sqrtf(d2o), din = sqrtf(d2i);
            float sgn = has_pos ? (has_neg ? (dout - din) : dout) : 0.f;
            float xs = (j == 0) ? xv.x : (j == 1) ? xv.y : (j == 2) ? xv.z : xv.w;
            float ls = (j == 0) ? lv.x : (j == 1) ? lv.y : (j == 2) ? lv.z : lv.w;
            int tt   = (j == 0) ? tv.x : (j == 1) ? tv.y : (j == 2) ? tv.z : tv.w;
            bool vb = (tt >= 0) && (tt < C_DIM);
            float prob = __expf(xs - ls);
            lsum += vb ? prob * sgn : 0.f;
        }
    }

    float r2 = wave_reduce_f(lsum);
    if (lane == 0) wsum[wid] = r2;
    __syncthreads();
    if (tid == 0) {
        float bsum = ((wsum[0] + wsum[1]) + (wsum[2] + wsum[3]))
                   + ((wsum[4] + wsum[5]) + (wsum[6] + wsum[7]));
        // hierarchical fence-free chain (validated R15): bound add committed (returned
        // value consumed) before per-bc counter bump; last-of-bc bumps gdone.
        float old = atomicAdd(&bound_part[bc << 5], bsum);
        asm volatile("" :: "v"(old));
        unsigned int o = atomicAdd(&cnt[bc << 5], 1u);
        int lastflag = 0;
        if (o == 15u) {
            unsigned int g = atomicAdd(gdone, 1u);
            lastflag = (g == 31u) ? 1 : 0;
        }
        sh_last = lastflag;
    }
    __syncthreads();
    if (!sh_last) return;

    // ---- globally-last block: finalize ----
    double s_ce = 0, s_in = 0, c_d = 0, c_b = 0;
    for (int k = tid; k < 1024; k += 512) {
        s_ce += (double)pce[k]; s_in += (double)pinter[k];
        int2 cc = pcnt[k]; c_d += (double)cc.x; c_b += (double)cc.y;
    }
    double sums[3]; double vin[3] = {s_ce, s_in, c_d * 4194304.0 + c_b};
    for (int q = 0; q < 3; ++q) {
        dred[tid] = vin[q];
        __syncthreads();
        for (int s2 = 256; s2; s2 >>= 1) { if (tid < s2) dred[tid] += dred[tid + s2]; __syncthreads(); }
        sums[q] = dred[0];
        __syncthreads();
    }
    __shared__ float bpart_s[32];
    if (tid < 32) bpart_s[tid] = atomicAdd(&bound_part[tid << 5], 0.0f);  // coherent reads
    __syncthreads();
    if (tid == 0) {
        double btot = 0.0;
        for (int k = 0; k < 32; ++k) btot += (double)bpart_s[k];
        double packed = sums[2];
        double cd = floor(packed / 4194304.0 + 1e-9);
        double cb = packed - cd * 4194304.0;
        double ce = sums[0] / (double)NPIX;
        double inter = sums[1];
        double card = cd + cb;
        double dice = 1.0 - (2.0 * inter + 1e-6) / (card + 1e-6);
        double dice_total = 0.1 * ce + 0.9 * dice;
        double bound = btot / (cb + 1e-8);
        out[0] = (float)(0.1 * ce + 0.8 * dice_total + 0.1 * bound);
    }
}

extern "C" void kernel_launch(void* const* d_in, const int* in_sizes, int n_in,
                              void* d_out, int out_size, void* d_ws, size_t ws_size,
                              hipStream_t stream) {
    const float* x = (const float*)d_in[0];
    const int* tgt = (const int*)d_in[1];
    float* out = (float*)d_out;

    char* ws = (char*)d_ws;
    float* pce    = (float*)(ws + 0);
    float* pinter = (float*)(ws + 4096);
    int2*  pcnt   = (int2*)(ws + 8192);
    float* bound_part = (float*)(ws + 16384);
    unsigned int* cnt = (unsigned int*)(ws + 20480);
    unsigned int* gdone = (unsigned int*)(ws + 24576);
    float* lse    = (float*)(ws + 65536);
    unsigned long long* wmask_g = (unsigned long long*)(ws + (size_t)(2u << 20));

    k_row<<<1024, 256, 0, stream>>>(x, tgt, lse, pce, pinter, pcnt, wmask_g,
                                    bound_part, cnt, gdone);
    k_cols<<<512, 512, 0, stream>>>(wmask_g, x, lse, tgt, pce, pinter, pcnt,
                                    bound_part, cnt, gdone, out);
}